// Round 2
// baseline (519.530 us; speedup 1.0000x reference)
//
#include <hip/hip_runtime.h>
#include <math.h>

#define HD 256   // hidden dim (fixed per problem)

// ---------------- CSR build ----------------

__global__ void init_deg_kernel(int* __restrict__ deg, int* __restrict__ cursor, int n) {
    int i = blockIdx.x * blockDim.x + threadIdx.x;
    if (i < n) { deg[i] = 1; cursor[i] = 0; }   // 1 = self loop
}

__global__ void count_deg_kernel(const int* __restrict__ col, int E, int* __restrict__ deg) {
    int e = blockIdx.x * blockDim.x + threadIdx.x;
    if (e < E) atomicAdd(&deg[col[e]], 1);
}

// single-block exclusive scan over deg -> offs; also dinv[v] = rsqrt(deg[v])
__global__ __launch_bounds__(1024) void scan_kernel(const int* __restrict__ deg,
                                                    int* __restrict__ offs,
                                                    float* __restrict__ dinv, int n) {
    __shared__ int ps[1024];
    int tid = threadIdx.x;
    int chunk = (n + 1023) >> 10;
    int beg = tid * chunk;
    int end = min(beg + chunk, n);
    int s = 0;
    for (int i = beg; i < end; ++i) s += deg[i];
    ps[tid] = s;
    __syncthreads();
    for (int off = 1; off < 1024; off <<= 1) {
        int t = (tid >= off) ? ps[tid - off] : 0;
        __syncthreads();
        ps[tid] += t;
        __syncthreads();
    }
    int run = ps[tid] - s;  // exclusive prefix
    for (int i = beg; i < end; ++i) {
        offs[i] = run;
        run += deg[i];
        dinv[i] = rsqrtf((float)deg[i]);
    }
    if (tid == 1023) offs[n] = ps[1023];
}

__global__ void fill_csr_kernel(const int* __restrict__ ei, int E, int N,
                                const int* __restrict__ offs,
                                int* __restrict__ cursor, int* __restrict__ csr) {
    int idx = blockIdx.x * blockDim.x + threadIdx.x;
    int tot = E + N;
    if (idx >= tot) return;
    int r, c;
    if (idx < E) { r = ei[idx]; c = ei[E + idx]; }
    else         { r = c = idx - E; }                 // self loop
    int slot = atomicAdd(&cursor[c], 1);
    csr[offs[c] + slot] = r;
}

// ---------------- aggregation ----------------
// Inputs are pre-scaled: h[u] = dinv[u] * (activation or z)[u], so the edge sum
// is a plain row sum.  One WAVE per node, float4 lanes (64 lanes x 16B = full row),
// neighbor loop unrolled x4 for memory-level parallelism.
// MODE 0: out[v] = dinv[v] * S                       (shared agg -> g)
// MODE 1: out[v] = dinv[v] * relu(dinv[v]*S + bias)  (hidden layers -> t, pre-scaled)

template<int MODE>
__global__ __launch_bounds__(256) void agg_kernel(const float* __restrict__ h,
                                                  const int* __restrict__ csr,
                                                  const int* __restrict__ offs,
                                                  const float* __restrict__ dinv,
                                                  const float* __restrict__ bias,
                                                  float* __restrict__ out, int N) {
    int gid  = blockIdx.x * blockDim.x + threadIdx.x;
    int v    = gid >> 6;
    int lane = gid & 63;
    if (v >= N) return;

    int beg = offs[v];
    int end = offs[v + 1];
    const float4* hp = (const float4*)h;   // row = 64 float4

    float4 acc = make_float4(0.f, 0.f, 0.f, 0.f);
    int i = beg;
    for (; i + 4 <= end; i += 4) {
        int u0 = csr[i], u1 = csr[i + 1], u2 = csr[i + 2], u3 = csr[i + 3];
        float4 r0 = hp[(size_t)u0 * 64 + lane];
        float4 r1 = hp[(size_t)u1 * 64 + lane];
        float4 r2 = hp[(size_t)u2 * 64 + lane];
        float4 r3 = hp[(size_t)u3 * 64 + lane];
        acc.x += (r0.x + r1.x) + (r2.x + r3.x);
        acc.y += (r0.y + r1.y) + (r2.y + r3.y);
        acc.z += (r0.z + r1.z) + (r2.z + r3.z);
        acc.w += (r0.w + r1.w) + (r2.w + r3.w);
    }
    for (; i < end; ++i) {
        int u = csr[i];
        float4 r = hp[(size_t)u * 64 + lane];
        acc.x += r.x; acc.y += r.y; acc.z += r.z; acc.w += r.w;
    }

    float dv = dinv[v];
    float4 o;
    if (MODE == 1) {
        float4 bv = ((const float4*)bias)[lane];
        o.x = dv * fmaxf(fmaf(dv, acc.x, bv.x), 0.f);
        o.y = dv * fmaxf(fmaf(dv, acc.y, bv.y), 0.f);
        o.z = dv * fmaxf(fmaf(dv, acc.z, bv.z), 0.f);
        o.w = dv * fmaxf(fmaf(dv, acc.w, bv.w), 0.f);
    } else {
        o.x = dv * acc.x; o.y = dv * acc.y; o.z = dv * acc.z; o.w = dv * acc.w;
    }
    ((float4*)out)[(size_t)v * 64 + lane] = o;
}

// ---------------- f32 GEMM: C[M,256] = A[M,256] @ W[256,256] ----------------
// BM=64, BN=64, BK=32, 64 threads (1 wave), 8x8 register tile.
// Intensity = 64 FMA / 16 LDS floats = 2 FLOP/B; tx,ty in 0..7 -> stride-8
// b128 LDS reads are only 2-way aliased (free).
// HEADS: virtual N=512, per-block select of W2/W3, bias, out2/out3.
// SCALE_A: multiply A rows by scale[row] while staging (dinv fold for layer 1).

template<bool SCALE_A, bool HEADS>
__global__ __launch_bounds__(64) void gemm_kernel(const float* __restrict__ A,
                                                  const float* __restrict__ Wa,
                                                  const float* __restrict__ Wb,
                                                  const float* __restrict__ ba,
                                                  const float* __restrict__ bb,
                                                  const float* __restrict__ scale,
                                                  float* __restrict__ Ca,
                                                  float* __restrict__ Cb, int M) {
    constexpr int BM = 64, BN = 64, BK = 32;
    __shared__ float As[BK][BM + 4];   // transposed A tile
    __shared__ float Ws[BK][BN + 4];

    const int tid  = threadIdx.x;
    const int row0 = blockIdx.x * BM;
    int col0 = blockIdx.y * BN;

    const float* W    = Wa;
    const float* bias = ba;
    float*       C    = Ca;
    if (HEADS && col0 >= HD) { W = Wb; bias = bb; C = Cb; col0 -= HD; }

    const int tx = tid & 7;    // 0..7 -> cols tx*8..+7
    const int ty = tid >> 3;   // 0..7 -> rows ty*8..+7

    float acc[8][8];
#pragma unroll
    for (int i = 0; i < 8; ++i)
#pragma unroll
        for (int j = 0; j < 8; ++j) acc[i][j] = 0.f;

    for (int k0 = 0; k0 < HD; k0 += BK) {
        // stage A tile transposed: As[k][m]
#pragma unroll
        for (int j = tid; j < (BM * BK) / 4; j += 64) {
            int r  = j >> 3;           // 0..63
            int kc = (j & 7) << 2;     // 0,4,...,28
            int row = row0 + r;
            float4 v = make_float4(0.f, 0.f, 0.f, 0.f);
            if (row < M) {
                v = *reinterpret_cast<const float4*>(&A[(size_t)row * HD + k0 + kc]);
                if (SCALE_A) {
                    float s = scale[row];
                    v.x *= s; v.y *= s; v.z *= s; v.w *= s;
                }
            }
            As[kc + 0][r] = v.x;
            As[kc + 1][r] = v.y;
            As[kc + 2][r] = v.z;
            As[kc + 3][r] = v.w;
        }
        // stage W tile (row-major)
#pragma unroll
        for (int j = tid; j < (BK * BN) / 4; j += 64) {
            int k = j >> 4;            // 0..31
            int c = (j & 15) << 2;     // 0,4,...,60
            *reinterpret_cast<float4*>(&Ws[k][c]) =
                *reinterpret_cast<const float4*>(&W[(size_t)(k0 + k) * HD + col0 + c]);
        }
        __syncthreads();

#pragma unroll
        for (int k = 0; k < BK; ++k) {
            float4 a0 = *reinterpret_cast<const float4*>(&As[k][ty << 3]);
            float4 a1 = *reinterpret_cast<const float4*>(&As[k][(ty << 3) + 4]);
            float4 b0 = *reinterpret_cast<const float4*>(&Ws[k][tx << 3]);
            float4 b1 = *reinterpret_cast<const float4*>(&Ws[k][(tx << 3) + 4]);
            float a_[8] = {a0.x, a0.y, a0.z, a0.w, a1.x, a1.y, a1.z, a1.w};
            float b_[8] = {b0.x, b0.y, b0.z, b0.w, b1.x, b1.y, b1.z, b1.w};
#pragma unroll
            for (int ii = 0; ii < 8; ++ii)
#pragma unroll
                for (int jj = 0; jj < 8; ++jj)
                    acc[ii][jj] = fmaf(a_[ii], b_[jj], acc[ii][jj]);
        }
        __syncthreads();
    }

    float badd[8];
#pragma unroll
    for (int j = 0; j < 8; ++j)
        badd[j] = HEADS ? bias[col0 + (tx << 3) + j] : 0.f;

#pragma unroll
    for (int i = 0; i < 8; ++i) {
        int row = row0 + (ty << 3) + i;
        if (row >= M) continue;
        float4 o0 = make_float4(acc[i][0] + badd[0], acc[i][1] + badd[1],
                                acc[i][2] + badd[2], acc[i][3] + badd[3]);
        float4 o1 = make_float4(acc[i][4] + badd[4], acc[i][5] + badd[5],
                                acc[i][6] + badd[6], acc[i][7] + badd[7]);
        *reinterpret_cast<float4*>(&C[(size_t)row * HD + col0 + (tx << 3)])     = o0;
        *reinterpret_cast<float4*>(&C[(size_t)row * HD + col0 + (tx << 3) + 4]) = o1;
    }
}

// ---------------- launch ----------------

static inline size_t align_up(size_t x, size_t a) { return (x + a - 1) & ~(a - 1); }

extern "C" void kernel_launch(void* const* d_in, const int* in_sizes, int n_in,
                              void* d_out, int out_size, void* d_ws, size_t ws_size,
                              hipStream_t stream) {
    const int N = in_sizes[0] / HD;
    const int E = in_sizes[1] / 2;

    const float* x   = (const float*)d_in[0];
    const int*   ei  = (const int*)d_in[1];
    const float* W1  = (const float*)d_in[2];
    const float* W11 = (const float*)d_in[3];
    const float* W2  = (const float*)d_in[4];
    const float* W3  = (const float*)d_in[5];
    const float* b1  = (const float*)d_in[6];
    const float* b11 = (const float*)d_in[7];
    const float* b2  = (const float*)d_in[8];
    const float* b3  = (const float*)d_in[9];

    float* out2 = (float*)d_out;
    float* out3 = out2 + (size_t)N * HD;

    // workspace carve
    char* p = (char*)d_ws;
    int*   deg    = (int*)p;   p += align_up((size_t)N * 4, 256);
    int*   offs   = (int*)p;   p += align_up((size_t)(N + 1) * 4, 256);
    int*   cursor = (int*)p;   p += align_up((size_t)N * 4, 256);
    float* dinv   = (float*)p; p += align_up((size_t)N * 4, 256);
    int*   csr    = (int*)p;   p += align_up((size_t)(E + N) * 4, 256);
    float* bufA   = (float*)p; p += align_up((size_t)N * HD * 4, 256);
    float* bufB   = (float*)p; p += align_up((size_t)N * HD * 4, 256);
    (void)ws_size; (void)n_in; (void)out_size;

    // --- CSR of incoming edges (with self loops); dinv from scan ---
    init_deg_kernel<<<(N + 255) / 256, 256, 0, stream>>>(deg, cursor, N);
    count_deg_kernel<<<(E + 255) / 256, 256, 0, stream>>>(ei + E, E, deg);
    scan_kernel<<<1, 1024, 0, stream>>>(deg, offs, dinv, N);
    fill_csr_kernel<<<(E + N + 255) / 256, 256, 0, stream>>>(ei, E, N, offs, cursor, csr);

    const int gemm_gx = (N + 63) / 64;
    const int agg_blocks = (N + 3) / 4;   // 4 waves (nodes) per 256-thread block

    // layer 1: z1 = (dinv .* x) @ W1 ; t1 = dinv*relu(dinv*sum + b1)
    gemm_kernel<true, false><<<dim3(gemm_gx, HD / 64), 64, 0, stream>>>(
        x, W1, nullptr, nullptr, nullptr, dinv, bufA, nullptr, N);
    agg_kernel<1><<<agg_blocks, 256, 0, stream>>>(bufA, csr, offs, dinv, b1, bufB, N);

    // layer 2: z2 = t1 @ W1_1 ; t2 = dinv*relu(dinv*sum + b1_1)
    gemm_kernel<false, false><<<dim3(gemm_gx, HD / 64), 64, 0, stream>>>(
        bufB, W11, nullptr, nullptr, nullptr, nullptr, bufA, nullptr, N);
    agg_kernel<1><<<agg_blocks, 256, 0, stream>>>(bufA, csr, offs, dinv, b11, bufB, N);

    // shared agg: g = dinv * sum(t2)
    agg_kernel<0><<<agg_blocks, 256, 0, stream>>>(bufB, csr, offs, dinv, nullptr, bufA, N);

    // fused heads: out2 = g@W2+b2 ; out3 = g@W3+b3  (virtual N=512)
    gemm_kernel<false, true><<<dim3(gemm_gx, 2 * HD / 64), 64, 0, stream>>>(
        bufA, W2, W3, b2, b3, nullptr, out2, out3, N);
}

// Round 3
// 397.460 us; speedup vs baseline: 1.3071x; 1.3071x over previous
//
#include <hip/hip_runtime.h>
#include <math.h>

#define HD 256   // hidden dim (fixed per problem)

// ---------------- CSR build ----------------

__global__ void init_deg_kernel(int* __restrict__ deg, int* __restrict__ cursor, int n) {
    int i = blockIdx.x * blockDim.x + threadIdx.x;
    if (i < n) { deg[i] = 1; cursor[i] = 0; }   // 1 = self loop
}

__global__ void count_deg_kernel(const int* __restrict__ col, int E, int* __restrict__ deg) {
    int e = blockIdx.x * blockDim.x + threadIdx.x;
    if (e < E) atomicAdd(&deg[col[e]], 1);
}

// single-block exclusive scan over deg -> offs; also dinv[v] = rsqrt(deg[v])
__global__ __launch_bounds__(1024) void scan_kernel(const int* __restrict__ deg,
                                                    int* __restrict__ offs,
                                                    float* __restrict__ dinv, int n) {
    __shared__ int ps[1024];
    int tid = threadIdx.x;
    int chunk = (n + 1023) >> 10;
    int beg = tid * chunk;
    int end = min(beg + chunk, n);
    int s = 0;
    for (int i = beg; i < end; ++i) s += deg[i];
    ps[tid] = s;
    __syncthreads();
    for (int off = 1; off < 1024; off <<= 1) {
        int t = (tid >= off) ? ps[tid - off] : 0;
        __syncthreads();
        ps[tid] += t;
        __syncthreads();
    }
    int run = ps[tid] - s;  // exclusive prefix
    for (int i = beg; i < end; ++i) {
        offs[i] = run;
        run += deg[i];
        dinv[i] = rsqrtf((float)deg[i]);
    }
    if (tid == 1023) offs[n] = ps[1023];
}

__global__ void fill_csr_kernel(const int* __restrict__ ei, int E, int N,
                                const int* __restrict__ offs,
                                int* __restrict__ cursor, int* __restrict__ csr) {
    int idx = blockIdx.x * blockDim.x + threadIdx.x;
    int tot = E + N;
    if (idx >= tot) return;
    int r, c;
    if (idx < E) { r = ei[idx]; c = ei[E + idx]; }
    else         { r = c = idx - E; }                 // self loop
    int slot = atomicAdd(&cursor[c], 1);
    csr[offs[c] + slot] = r;
}

// ---------------- aggregation ----------------
// Inputs pre-scaled (h[u] = dinv[u]*act[u]) so the edge sum is a plain row sum.
// One WAVE per node, float4 lanes, neighbor loop unrolled x4.
// MODE 0: out[v] = dinv[v] * S
// MODE 1: out[v] = dinv[v] * relu(dinv[v]*S + bias)   (pre-scaled for next GEMM)

template<int MODE>
__global__ __launch_bounds__(256) void agg_kernel(const float* __restrict__ h,
                                                  const int* __restrict__ csr,
                                                  const int* __restrict__ offs,
                                                  const float* __restrict__ dinv,
                                                  const float* __restrict__ bias,
                                                  float* __restrict__ out, int N) {
    int gid  = blockIdx.x * blockDim.x + threadIdx.x;
    int v    = gid >> 6;
    int lane = gid & 63;
    if (v >= N) return;

    int beg = offs[v];
    int end = offs[v + 1];
    const float4* hp = (const float4*)h;   // row = 64 float4

    float4 acc = make_float4(0.f, 0.f, 0.f, 0.f);
    int i = beg;
    for (; i + 4 <= end; i += 4) {
        int u0 = csr[i], u1 = csr[i + 1], u2 = csr[i + 2], u3 = csr[i + 3];
        float4 r0 = hp[(size_t)u0 * 64 + lane];
        float4 r1 = hp[(size_t)u1 * 64 + lane];
        float4 r2 = hp[(size_t)u2 * 64 + lane];
        float4 r3 = hp[(size_t)u3 * 64 + lane];
        acc.x += (r0.x + r1.x) + (r2.x + r3.x);
        acc.y += (r0.y + r1.y) + (r2.y + r3.y);
        acc.z += (r0.z + r1.z) + (r2.z + r3.z);
        acc.w += (r0.w + r1.w) + (r2.w + r3.w);
    }
    for (; i < end; ++i) {
        int u = csr[i];
        float4 r = hp[(size_t)u * 64 + lane];
        acc.x += r.x; acc.y += r.y; acc.z += r.z; acc.w += r.w;
    }

    float dv = dinv[v];
    float4 o;
    if (MODE == 1) {
        float4 bv = ((const float4*)bias)[lane];
        o.x = dv * fmaxf(fmaf(dv, acc.x, bv.x), 0.f);
        o.y = dv * fmaxf(fmaf(dv, acc.y, bv.y), 0.f);
        o.z = dv * fmaxf(fmaf(dv, acc.z, bv.z), 0.f);
        o.w = dv * fmaxf(fmaf(dv, acc.w, bv.w), 0.f);
    } else {
        o.x = dv * acc.x; o.y = dv * acc.y; o.z = dv * acc.z; o.w = dv * acc.w;
    }
    ((float4*)out)[(size_t)v * 64 + lane] = o;
}

// ---------------- f32 GEMM: C[M,256] = A[M,256] @ W[256,256] ----------------
// BM=64, BN=128, BK=32, 128 threads (2 waves), 8x8 register tile (2.0 FLOP/B).
// Fragment cols = {4tx..+3} u {64+4tx..+3}; rows = {4ty..+3} u {32+4ty..+3}:
// every ds_read_b128 covers a CONTIGUOUS span -> no bank conflicts.
// HEADS: virtual N=512, per-block select of W2/W3, bias, out2/out3.
// SCALE_A: multiply A rows by scale[row] while staging (dinv fold for layer 1).

template<bool SCALE_A, bool HEADS>
__global__ __launch_bounds__(128) void gemm_kernel(const float* __restrict__ A,
                                                   const float* __restrict__ Wa,
                                                   const float* __restrict__ Wb,
                                                   const float* __restrict__ ba,
                                                   const float* __restrict__ bb,
                                                   const float* __restrict__ scale,
                                                   float* __restrict__ Ca,
                                                   float* __restrict__ Cb, int M) {
    constexpr int BM = 64, BN = 128, BK = 32;
    __shared__ float As[BK][BM];   // transposed A tile [k][m], 8 KB
    __shared__ float Ws[BK][BN];   // [k][n], 16 KB

    const int tid  = threadIdx.x;
    const int row0 = blockIdx.x * BM;
    int col0 = blockIdx.y * BN;

    const float* W    = Wa;
    const float* bias = ba;
    float*       C    = Ca;
    if (HEADS && col0 >= HD) { W = Wb; bias = bb; C = Cb; col0 -= HD; }

    const int tx = tid & 15;    // cols 4tx..+3 and 64+4tx..+3
    const int ty = tid >> 4;    // rows 4ty..+3 and 32+4ty..+3  (ty 0..7)

    // staging roles
    const int sa_m  = tid >> 1;          // A row within tile (0..63)
    const int sa_ks = (tid & 1) * 16;    // k-half (0 or 16)
    const int sw_kb = tid >> 5;          // W k sub-row (0..3)
    const int sw_c  = (tid & 31) * 4;    // W col chunk (0..124)

    const bool a_ok = (row0 + sa_m) < M;
    float a_scale = 1.f;
    if (SCALE_A && a_ok) a_scale = scale[row0 + sa_m];
    const float* Arow = A + (size_t)(row0 + sa_m) * HD + sa_ks;

    float acc[8][8];
#pragma unroll
    for (int i = 0; i < 8; ++i)
#pragma unroll
        for (int j = 0; j < 8; ++j) acc[i][j] = 0.f;

    for (int k0 = 0; k0 < HD; k0 += BK) {
        // ---- stage A (transposed) ----
        float4 av[4];
#pragma unroll
        for (int q = 0; q < 4; ++q) {
            av[q] = make_float4(0.f, 0.f, 0.f, 0.f);
            if (a_ok) {
                av[q] = *reinterpret_cast<const float4*>(&Arow[k0 + q * 4]);
                if (SCALE_A) { av[q].x *= a_scale; av[q].y *= a_scale; av[q].z *= a_scale; av[q].w *= a_scale; }
            }
        }
#pragma unroll
        for (int q = 0; q < 4; ++q) {
            As[sa_ks + q * 4 + 0][sa_m] = av[q].x;
            As[sa_ks + q * 4 + 1][sa_m] = av[q].y;
            As[sa_ks + q * 4 + 2][sa_m] = av[q].z;
            As[sa_ks + q * 4 + 3][sa_m] = av[q].w;
        }
        // ---- stage W ----
#pragma unroll
        for (int g = 0; g < 8; ++g) {
            int k = g * 4 + sw_kb;
            float4 wv = *reinterpret_cast<const float4*>(&W[(size_t)(k0 + k) * HD + col0 + sw_c]);
            *reinterpret_cast<float4*>(&Ws[k][sw_c]) = wv;
        }
        __syncthreads();

#pragma unroll 8
        for (int k = 0; k < BK; ++k) {
            float4 a0 = *reinterpret_cast<const float4*>(&As[k][ty * 4]);
            float4 a1 = *reinterpret_cast<const float4*>(&As[k][32 + ty * 4]);
            float4 b0 = *reinterpret_cast<const float4*>(&Ws[k][tx * 4]);
            float4 b1 = *reinterpret_cast<const float4*>(&Ws[k][64 + tx * 4]);
            float a_[8] = {a0.x, a0.y, a0.z, a0.w, a1.x, a1.y, a1.z, a1.w};
            float b_[8] = {b0.x, b0.y, b0.z, b0.w, b1.x, b1.y, b1.z, b1.w};
#pragma unroll
            for (int ii = 0; ii < 8; ++ii)
#pragma unroll
                for (int jj = 0; jj < 8; ++jj)
                    acc[ii][jj] = fmaf(a_[ii], b_[jj], acc[ii][jj]);
        }
        __syncthreads();
    }

    float badd[8];
#pragma unroll
    for (int j = 0; j < 8; ++j) {
        int c = (j < 4) ? (col0 + tx * 4 + j) : (col0 + 64 + tx * 4 + (j - 4));
        badd[j] = HEADS ? bias[c] : 0.f;
    }

#pragma unroll
    for (int i = 0; i < 8; ++i) {
        int row = row0 + ((i < 4) ? (ty * 4 + i) : (32 + ty * 4 + (i - 4)));
        if (row >= M) continue;
        float4 o0 = make_float4(acc[i][0] + badd[0], acc[i][1] + badd[1],
                                acc[i][2] + badd[2], acc[i][3] + badd[3]);
        float4 o1 = make_float4(acc[i][4] + badd[4], acc[i][5] + badd[5],
                                acc[i][6] + badd[6], acc[i][7] + badd[7]);
        *reinterpret_cast<float4*>(&C[(size_t)row * HD + col0 + tx * 4])      = o0;
        *reinterpret_cast<float4*>(&C[(size_t)row * HD + col0 + 64 + tx * 4]) = o1;
    }
}

// ---------------- launch ----------------

static inline size_t align_up(size_t x, size_t a) { return (x + a - 1) & ~(a - 1); }

extern "C" void kernel_launch(void* const* d_in, const int* in_sizes, int n_in,
                              void* d_out, int out_size, void* d_ws, size_t ws_size,
                              hipStream_t stream) {
    const int N = in_sizes[0] / HD;
    const int E = in_sizes[1] / 2;

    const float* x   = (const float*)d_in[0];
    const int*   ei  = (const int*)d_in[1];
    const float* W1  = (const float*)d_in[2];
    const float* W11 = (const float*)d_in[3];
    const float* W2  = (const float*)d_in[4];
    const float* W3  = (const float*)d_in[5];
    const float* b1  = (const float*)d_in[6];
    const float* b11 = (const float*)d_in[7];
    const float* b2  = (const float*)d_in[8];
    const float* b3  = (const float*)d_in[9];

    float* out2 = (float*)d_out;
    float* out3 = out2 + (size_t)N * HD;

    // workspace carve
    char* p = (char*)d_ws;
    int*   deg    = (int*)p;   p += align_up((size_t)N * 4, 256);
    int*   offs   = (int*)p;   p += align_up((size_t)(N + 1) * 4, 256);
    int*   cursor = (int*)p;   p += align_up((size_t)N * 4, 256);
    float* dinv   = (float*)p; p += align_up((size_t)N * 4, 256);
    int*   csr    = (int*)p;   p += align_up((size_t)(E + N) * 4, 256);
    float* bufA   = (float*)p; p += align_up((size_t)N * HD * 4, 256);
    float* bufB   = (float*)p; p += align_up((size_t)N * HD * 4, 256);
    (void)ws_size; (void)n_in; (void)out_size;

    // --- CSR of incoming edges (with self loops); dinv from scan ---
    init_deg_kernel<<<(N + 255) / 256, 256, 0, stream>>>(deg, cursor, N);
    count_deg_kernel<<<(E + 255) / 256, 256, 0, stream>>>(ei + E, E, deg);
    scan_kernel<<<1, 1024, 0, stream>>>(deg, offs, dinv, N);
    fill_csr_kernel<<<(E + N + 255) / 256, 256, 0, stream>>>(ei, E, N, offs, cursor, csr);

    const int gemm_gx = (N + 63) / 64;
    const int agg_blocks = (N + 3) / 4;   // 4 waves (nodes) per 256-thread block

    // layer 1: z1 = (dinv .* x) @ W1 ; t1 = dinv*relu(dinv*sum + b1)
    gemm_kernel<true, false><<<dim3(gemm_gx, HD / 128), 128, 0, stream>>>(
        x, W1, nullptr, nullptr, nullptr, dinv, bufA, nullptr, N);
    agg_kernel<1><<<agg_blocks, 256, 0, stream>>>(bufA, csr, offs, dinv, b1, bufB, N);

    // layer 2: z2 = t1 @ W1_1 ; t2 = dinv*relu(dinv*sum + b1_1)
    gemm_kernel<false, false><<<dim3(gemm_gx, HD / 128), 128, 0, stream>>>(
        bufB, W11, nullptr, nullptr, nullptr, nullptr, bufA, nullptr, N);
    agg_kernel<1><<<agg_blocks, 256, 0, stream>>>(bufA, csr, offs, dinv, b11, bufB, N);

    // shared agg: g = dinv * sum(t2)
    agg_kernel<0><<<agg_blocks, 256, 0, stream>>>(bufB, csr, offs, dinv, nullptr, bufA, N);

    // fused heads: out2 = g@W2+b2 ; out3 = g@W3+b3  (virtual N=512)
    gemm_kernel<false, true><<<dim3(gemm_gx, 2 * HD / 128), 128, 0, stream>>>(
        bufA, W2, W3, b2, b3, nullptr, out2, out3, N);
}